// Round 8
// baseline (68.538 us; speedup 1.0000x reference)
//
#include <hip/hip_runtime.h>

// IMMLoss: B=32 groups, M=4 rows, D=196608 features, f32.
// loss = mean_b( wtout[b] * (mean K(st,st) + mean K(sr,sr) - 2*mean K(st,sr)) )
// Two-kernel structure (fusion regressed 2x). Streaming Gram accumulation:
// TB=64, NBUF=3 (24.5KB LDS -> 6 blocks/CU), counted vmcnt + raw s_barrier,
// per-wave complete pair-sets.

constexpr int NB = 32;        // groups
constexpr int MM = 4;         // rows per group (8 combined: 4 st + 4 sr)
constexpr int DD = 196608;    // feature dim
constexpr int D4 = DD / 4;    // 49152 float4 per row
constexpr int BPG = 48;       // blocks per group -> 1536 blocks = 6/CU exact
constexpr int NTHREADS = 256; // 4 waves
constexpr int TB = 64;        // columns per stage
constexpr int CHUNK4 = D4 / BPG;   // 1024 float4 columns per block
constexpr int NITER = CHUNK4 / TB; // 16
constexpr int NBUF = 3;            // 3 x 8KB buffers, 2 stages in flight
constexpr int NACC = 36;           // 10 ss + 10 rr + 16 cross

__device__ __forceinline__ void gl_lds16(const float4* gsrc, float4* lds_dst) {
    __builtin_amdgcn_global_load_lds(
        (const __attribute__((address_space(1))) void*)gsrc,
        (__attribute__((address_space(3))) void*)lds_dst,
        16, 0, 0);
}

__device__ __forceinline__ float dot4(const float4& a, const float4& b) {
    return a.x * b.x + a.y * b.y + a.z * b.z + a.w * b.w;
}

__global__ __launch_bounds__(NTHREADS, 6) void mmd_partial_kernel(
    const float* __restrict__ st, const float* __restrict__ sr,
    float* __restrict__ partial)
{
    __shared__ float4 buf[NBUF][8][TB];   // 24 KiB
    __shared__ float red[4][10];

    const int b    = blockIdx.x / BPG;
    const int blk  = blockIdx.x % BPG;
    const int c0   = blk * CHUNK4;
    const int tid  = threadIdx.x;
    const int wave = tid >> 6;
    const int lane = tid & 63;

    const float4* stb = reinterpret_cast<const float4*>(st) + (size_t)b * MM * D4;
    const float4* srb = reinterpret_cast<const float4*>(sr) + (size_t)b * MM * D4;

    // This wave stages rows r0, r0+1 (rows 0-3 = st, 4-7 = sr).
    const int r0 = 2 * wave;
    const float4* g0 = (r0 < 4 ? stb + (size_t)r0 * D4
                                : srb + (size_t)(r0 - 4) * D4) + c0 + lane;
    const float4* g1 = (r0 + 1 < 4 ? stb + (size_t)(r0 + 1) * D4
                                    : srb + (size_t)(r0 - 3) * D4) + c0 + lane;

    // Stage s: this wave issues 2 x (64 lanes x 16B = 1KB). LDS dest is the
    // wave-uniform row base; HW adds lane*16. vmcnt is per-wave.
    auto stage = [&](int s) {
        const int m = s % NBUF;
        gl_lds16(g0 + s * TB, &buf[m][r0][0]);
        gl_lds16(g1 + s * TB, &buf[m][r0 + 1][0]);
    };

    float acc[10];
#pragma unroll
    for (int k = 0; k < 10; ++k) acc[k] = 0.0f;

    stage(0);
    stage(1);   // 2 stages (4 loads/wave) in flight

#pragma unroll
    for (int t = 0; t < NITER; ++t) {
        // My ds_reads of tile t-1 have sampled LDS -> safe to overwrite the
        // oldest buffer after the barrier.
        asm volatile("s_waitcnt lgkmcnt(0)" ::: "memory");
        // My 2 loads of stage t have landed (stage t+1's 2 may remain).
        if (t == NITER - 1) asm volatile("s_waitcnt vmcnt(0)" ::: "memory");
        else                asm volatile("s_waitcnt vmcnt(2)" ::: "memory");
        // Raw barrier (no drain): all waves' stage-t rows are in LDS and all
        // waves are done reading tile t-1.
        __builtin_amdgcn_s_barrier();
        if (t + 2 < NITER) stage(t + 2);   // overwrite buffer of tile t-1

        const int m = t % NBUF;
        if (wave == 0) {
            float4 x[4];
#pragma unroll
            for (int r = 0; r < 4; ++r) x[r] = buf[m][r][lane];
            int a = 0;
#pragma unroll
            for (int i = 0; i < MM; ++i)
#pragma unroll
                for (int j = i; j < MM; ++j) { acc[a] += dot4(x[i], x[j]); ++a; }
        } else if (wave == 1) {
            float4 x[4];
#pragma unroll
            for (int r = 0; r < 4; ++r) x[r] = buf[m][4 + r][lane];
            int a = 0;
#pragma unroll
            for (int i = 0; i < MM; ++i)
#pragma unroll
                for (int j = i; j < MM; ++j) { acc[a] += dot4(x[i], x[j]); ++a; }
        } else {
            const int ib = (wave == 2) ? 0 : 2;
            float4 xi[2], y[4];
            xi[0] = buf[m][ib][lane];
            xi[1] = buf[m][ib + 1][lane];
#pragma unroll
            for (int j = 0; j < 4; ++j) y[j] = buf[m][4 + j][lane];
            int a = 0;
#pragma unroll
            for (int i = 0; i < 2; ++i)
#pragma unroll
                for (int j = 0; j < 4; ++j) { acc[a] += dot4(xi[i], y[j]); ++a; }
        }
    }

    // 64-lane butterfly reduce of this wave's (complete) pairs.
#pragma unroll
    for (int k = 0; k < 10; ++k) {
        float v = acc[k];
        for (int off = 32; off > 0; off >>= 1) v += __shfl_down(v, off, 64);
        acc[k] = v;
    }
    if (lane == 0) {
#pragma unroll
        for (int k = 0; k < 10; ++k) red[wave][k] = acc[k];
    }
    __syncthreads();

    // Global pair order: 0..9 ss, 10..19 rr, 20..27 cross(i=0,1), 28..35 cross(i=2,3).
    if (tid < NACC) {
        const int k = tid;
        float v;
        if (k < 10)      v = red[0][k];
        else if (k < 20) v = red[1][k - 10];
        else if (k < 28) v = red[2][k - 20];
        else             v = red[3][k - 28];
        partial[(size_t)blockIdx.x * NACC + k] = v;
    }
}

__global__ __launch_bounds__(1024) void mmd_final_kernel(
    const float* __restrict__ partial, const float* __restrict__ wt,
    const float* __restrict__ wtout, float* __restrict__ out)
{
    __shared__ float acc_s[NB][NACC];
    for (int p = threadIdx.x; p < NB * NACC; p += 1024) {
        const int b = p / NACC;
        const int k = p % NACC;
        float s = 0.0f;
        for (int blk = 0; blk < BPG; ++blk)
            s += partial[((size_t)b * BPG + blk) * NACC + k];
        acc_s[b][k] = s;
    }
    __syncthreads();

    __shared__ float lds[NB];
    const int b = threadIdx.x;
    if (b < NB) {
        const float* a = acc_s[b];
        float ss[MM][MM], rr[MM][MM], sg[MM][MM];
        {
            int k = 0;
            for (int i = 0; i < MM; ++i)
                for (int j = i; j < MM; ++j) { ss[i][j] = a[k]; ss[j][i] = a[k]; ++k; }
            for (int i = 0; i < MM; ++i)
                for (int j = i; j < MM; ++j) { rr[i][j] = a[k]; rr[j][i] = a[k]; ++k; }
            for (int i = 0; i < MM; ++i)
                for (int j = 0; j < MM; ++j) { sg[i][j] = a[k]; ++k; }
        }

        const float w    = wt[b];
        const float invD = 1.0f / (float)DD;  // sigma = 1
        auto kv = [&](float d2) -> float {
            d2 = fmaxf(d2, 1e-12f);
            float dist = sqrtf(d2) * invD;
            float e = -dist * w;
            e = fminf(fmaxf(e, -1e6f), 0.0f);
            return expf(e);
        };

        float mss = 0.0f, mrr = 0.0f, msr = 0.0f;
        for (int i = 0; i < MM; ++i) {
            for (int j = 0; j < MM; ++j) {
                mss += kv(ss[i][i] + ss[j][j] - 2.0f * ss[i][j]);
                mrr += kv(rr[i][i] + rr[j][j] - 2.0f * rr[i][j]);
                msr += kv(ss[i][i] + rr[j][j] - 2.0f * sg[i][j]);
            }
        }
        const float inv16 = 1.0f / 16.0f;
        float loss_raw = mss * inv16 + mrr * inv16 - 2.0f * (msr * inv16);
        lds[b] = wtout[b] * loss_raw;
    }
    __syncthreads();
    if (threadIdx.x == 0) {
        float s = 0.0f;
        for (int i = 0; i < NB; ++i) s += lds[i];
        out[0] = s / (float)NB;
    }
}

extern "C" void kernel_launch(void* const* d_in, const int* in_sizes, int n_in,
                              void* d_out, int out_size, void* d_ws, size_t ws_size,
                              hipStream_t stream) {
    const float* f_st  = (const float*)d_in[0];
    const float* f_sr  = (const float*)d_in[1];
    const float* wt    = (const float*)d_in[2];
    const float* wtout = (const float*)d_in[3];
    float* out     = (float*)d_out;
    float* partial = (float*)d_ws;   // NB*BPG*NACC floats = 221184 B

    mmd_partial_kernel<<<NB * BPG, NTHREADS, 0, stream>>>(f_st, f_sr, partial);
    mmd_final_kernel<<<1, 1024, 0, stream>>>(partial, wt, wtout, out);
}

// Round 9
// 43.760 us; speedup vs baseline: 1.5662x; 1.5662x over previous
//
#include <hip/hip_runtime.h>

// IMMLoss: B=32 groups, M=4 rows, D=196608 features, f32.
// loss = mean_b( wtout[b] * (mean K(st,st) + mean K(sr,sr) - 2*mean K(st,sr)) )
// Two-kernel structure. Partial kernel = R5's proven streaming geometry
// (TB=128, NBUF=3, 3 blocks/CU, counted vmcnt + raw s_barrier), 43.2us.
// R9 change: partial layout transposed to [k][b][blk] so the final kernel's
// per-thread 24-element sums read consecutive floats (coalesced).

constexpr int NB = 32;        // groups
constexpr int MM = 4;         // rows per group (8 combined: 4 st + 4 sr)
constexpr int DD = 196608;    // feature dim
constexpr int D4 = DD / 4;    // 49152 float4 per row
constexpr int BPG = 24;       // blocks per group -> 768 blocks = 3/CU exact
constexpr int NBLOCKS = NB * BPG;
constexpr int NTHREADS = 256; // 4 waves
constexpr int TB = 128;       // columns per stage
constexpr int CHUNK4 = D4 / BPG;   // 2048 float4 columns per block
constexpr int NITER = CHUNK4 / TB; // 16
constexpr int NBUF = 3;            // 3 x 16KB buffers, 2 stages in flight
constexpr int NPAIR = 18;          // pairs per thread (36 split across 2 sets)
constexpr int NACC = 36;

__device__ __forceinline__ void gl_lds16(const float4* gsrc, float4* lds_dst) {
    __builtin_amdgcn_global_load_lds(
        (const __attribute__((address_space(1))) void*)gsrc,
        (__attribute__((address_space(3))) void*)lds_dst,
        16, 0, 0);
}

__device__ __forceinline__ float dot4(const float4& a, const float4& b) {
    return a.x * b.x + a.y * b.y + a.z * b.z + a.w * b.w;
}

__global__ __launch_bounds__(NTHREADS) void mmd_partial_kernel(
    const float* __restrict__ st, const float* __restrict__ sr,
    float* __restrict__ partial)
{
    __shared__ float4 buf[NBUF][8][TB];   // 48 KiB
    __shared__ float red[4][NPAIR];

    const int b    = blockIdx.x / BPG;
    const int blk  = blockIdx.x % BPG;
    const int c0   = blk * CHUNK4;
    const int tid  = threadIdx.x;
    const int wave = tid >> 6;
    const int lane = tid & 63;
    const int col  = tid & (TB - 1);   // column within tile (2 threads/col)
    const int set  = wave >> 1;        // 0: ss+cross(i=0,1)  1: rr+cross(i=2,3)

    const float4* stb = reinterpret_cast<const float4*>(st) + (size_t)b * MM * D4;
    const float4* srb = reinterpret_cast<const float4*>(sr) + (size_t)b * MM * D4;

    // This wave stages rows r0, r0+1 (rows 0-3 = st, 4-7 = sr).
    const int r0 = 2 * wave;
    const float4* g0 = (r0 < 4 ? stb + (size_t)r0 * D4
                                : srb + (size_t)(r0 - 4) * D4) + c0 + lane;
    const float4* g1 = (r0 + 1 < 4 ? stb + (size_t)(r0 + 1) * D4
                                    : srb + (size_t)(r0 - 3) * D4) + c0 + lane;

    // Stage s: this wave issues 4 x (64 lanes x 16B = 1KB). LDS dest is the
    // wave-uniform row base; HW adds lane*16. vmcnt is per-wave.
    auto stage = [&](int s) {
        const int m   = s % NBUF;
        const int off = s * TB;
        gl_lds16(g0 + off,      &buf[m][r0][0]);
        gl_lds16(g0 + off + 64, &buf[m][r0][64]);
        gl_lds16(g1 + off,      &buf[m][r0 + 1][0]);
        gl_lds16(g1 + off + 64, &buf[m][r0 + 1][64]);
    };

    float acc[NPAIR];
#pragma unroll
    for (int k = 0; k < NPAIR; ++k) acc[k] = 0.0f;

    stage(0);
    stage(1);   // 2 stages (8 loads/wave) in flight

#pragma unroll
    for (int t = 0; t < NITER; ++t) {
        // My ds_reads of tile t-1 have sampled LDS -> safe for others to
        // overwrite the oldest buffer after the barrier.
        asm volatile("s_waitcnt lgkmcnt(0)" ::: "memory");
        // My 4 loads of stage t have landed (stage t+1's 4 may remain).
        if (t == NITER - 1) asm volatile("s_waitcnt vmcnt(0)" ::: "memory");
        else                asm volatile("s_waitcnt vmcnt(4)" ::: "memory");
        // Raw barrier (no drain): all waves' stage-t rows are in LDS and all
        // waves are done reading tile t-1.
        __builtin_amdgcn_s_barrier();
        if (t + 2 < NITER) stage(t + 2);   // overwrite buffer of tile t-1

        const int m = t % NBUF;
        float4 x[8];
#pragma unroll
        for (int r = 0; r < 8; ++r) x[r] = buf[m][r][col];

        if (set == 0) {
            int a = 0;
#pragma unroll
            for (int i = 0; i < MM; ++i)
#pragma unroll
                for (int j = i; j < MM; ++j) { acc[a] += dot4(x[i], x[j]); ++a; }
#pragma unroll
            for (int i = 0; i < 2; ++i)
#pragma unroll
                for (int j = 0; j < MM; ++j) { acc[a] += dot4(x[i], x[4 + j]); ++a; }
        } else {
            int a = 0;
#pragma unroll
            for (int i = 0; i < MM; ++i)
#pragma unroll
                for (int j = i; j < MM; ++j) { acc[a] += dot4(x[4 + i], x[4 + j]); ++a; }
#pragma unroll
            for (int i = 2; i < 4; ++i)
#pragma unroll
                for (int j = 0; j < MM; ++j) { acc[a] += dot4(x[i], x[4 + j]); ++a; }
        }
    }

    // 64-lane butterfly reduce (sums the 64 columns this wave covered).
#pragma unroll
    for (int k = 0; k < NPAIR; ++k) {
        float v = acc[k];
        for (int off = 32; off > 0; off >>= 1) v += __shfl_down(v, off, 64);
        acc[k] = v;
    }
    if (lane == 0) {
#pragma unroll
        for (int k = 0; k < NPAIR; ++k) red[wave][k] = acc[k];
    }
    __syncthreads();

    // Global pair order: k=0..9 ss, 10..19 rr, 20..27 cross(i=0,1), 28..35 cross(i=2,3).
    // Transposed partial layout: partial[(k*NB + b)*BPG + blk].
    if (tid < NACC) {
        const int k = tid;
        float v;
        if (k < 10)       v = red[0][k]      + red[1][k];        // ss  (set A)
        else if (k < 20)  v = red[2][k - 10] + red[3][k - 10];   // rr  (set B)
        else if (k < 28)  v = red[0][10 + (k - 20)] + red[1][10 + (k - 20)]; // cross i=0,1
        else              v = red[2][10 + (k - 28)] + red[3][10 + (k - 28)]; // cross i=2,3
        partial[((size_t)k * NB + b) * BPG + blk] = v;
    }
}

__global__ __launch_bounds__(1024) void mmd_final_kernel(
    const float* __restrict__ partial, const float* __restrict__ wt,
    const float* __restrict__ wtout, float* __restrict__ out)
{
    __shared__ float acc_s[NACC][NB];   // [k][b]
    // Each (k,b) thread sums its 24 CONSECUTIVE partials (coalesced reads,
    // same q-order as before -> bitwise-identical result).
    for (int p = threadIdx.x; p < NB * NACC; p += 1024) {
        const int k = p >> 5;          // p / 32
        const int b = p & 31;          // p % 32
        const float* src = partial + ((size_t)k * NB + b) * BPG;
        float s = 0.0f;
#pragma unroll
        for (int q = 0; q < BPG; ++q) s += src[q];
        acc_s[k][b] = s;
    }
    __syncthreads();

    __shared__ float lds[NB];
    const int b = threadIdx.x;
    if (b < NB) {
        float a[NACC];
#pragma unroll
        for (int k = 0; k < NACC; ++k) a[k] = acc_s[k][b];   // lane b -> bank b

        float ss[MM][MM], rr[MM][MM], sg[MM][MM];
        {
            int k = 0;
            for (int i = 0; i < MM; ++i)
                for (int j = i; j < MM; ++j) { ss[i][j] = a[k]; ss[j][i] = a[k]; ++k; }
            for (int i = 0; i < MM; ++i)
                for (int j = i; j < MM; ++j) { rr[i][j] = a[k]; rr[j][i] = a[k]; ++k; }
            for (int i = 0; i < MM; ++i)
                for (int j = 0; j < MM; ++j) { sg[i][j] = a[k]; ++k; }
        }

        const float w    = wt[b];
        const float invD = 1.0f / (float)DD;  // sigma = 1
        auto kv = [&](float d2) -> float {
            d2 = fmaxf(d2, 1e-12f);
            float dist = sqrtf(d2) * invD;
            float e = -dist * w;
            e = fminf(fmaxf(e, -1e6f), 0.0f);
            return expf(e);
        };

        float mss = 0.0f, mrr = 0.0f, msr = 0.0f;
        for (int i = 0; i < MM; ++i) {
            for (int j = 0; j < MM; ++j) {
                mss += kv(ss[i][i] + ss[j][j] - 2.0f * ss[i][j]);
                mrr += kv(rr[i][i] + rr[j][j] - 2.0f * rr[i][j]);
                msr += kv(ss[i][i] + rr[j][j] - 2.0f * sg[i][j]);
            }
        }
        const float inv16 = 1.0f / 16.0f;
        float loss_raw = mss * inv16 + mrr * inv16 - 2.0f * (msr * inv16);
        lds[b] = wtout[b] * loss_raw;
    }
    __syncthreads();
    if (threadIdx.x == 0) {
        float s = 0.0f;
        for (int i = 0; i < NB; ++i) s += lds[i];
        out[0] = s / (float)NB;
    }
}

extern "C" void kernel_launch(void* const* d_in, const int* in_sizes, int n_in,
                              void* d_out, int out_size, void* d_ws, size_t ws_size,
                              hipStream_t stream) {
    const float* f_st  = (const float*)d_in[0];
    const float* f_sr  = (const float*)d_in[1];
    const float* wt    = (const float*)d_in[2];
    const float* wtout = (const float*)d_in[3];
    float* out     = (float*)d_out;
    float* partial = (float*)d_ws;   // NACC*NB*BPG floats = 110592 B

    mmd_partial_kernel<<<NBLOCKS, NTHREADS, 0, stream>>>(f_st, f_sr, partial);
    mmd_final_kernel<<<1, 1024, 0, stream>>>(partial, wt, wtout, out);
}

// Round 10
// 43.388 us; speedup vs baseline: 1.5797x; 1.0086x over previous
//
#include <hip/hip_runtime.h>

// IMMLoss: B=32 groups, M=4 rows, D=196608 features, f32.
// loss = mean_b( wtout[b] * (mean K(st,st) + mean K(sr,sr) - 2*mean K(st,sr)) )
// Two-kernel structure. R10: minimize DRAM streams/CU (16 = 2 blocks/CU x 8
// rows) + deepen the counted-vmcnt pipeline: TB=128, NBUF=4 (64KB LDS),
// prefetch depth 3, steady-state vmcnt(8), raw s_barrier, never drains.

constexpr int NB = 32;        // groups
constexpr int MM = 4;         // rows per group (8 combined: 4 st + 4 sr)
constexpr int DD = 196608;    // feature dim
constexpr int D4 = DD / 4;    // 49152 float4 per row
constexpr int BPG = 16;       // blocks per group -> 512 blocks = 2/CU exact
constexpr int NBLOCKS = NB * BPG;
constexpr int NTHREADS = 256; // 4 waves
constexpr int TB = 128;       // columns per stage
constexpr int CHUNK4 = D4 / BPG;   // 3072 float4 columns per block
constexpr int NITER = CHUNK4 / TB; // 24
constexpr int NBUF = 4;            // 4 x 16KB buffers, 3 stages in flight
constexpr int NPAIR = 18;          // pairs per thread (36 split across 2 sets)
constexpr int NACC = 36;

__device__ __forceinline__ void gl_lds16(const float4* gsrc, float4* lds_dst) {
    __builtin_amdgcn_global_load_lds(
        (const __attribute__((address_space(1))) void*)gsrc,
        (__attribute__((address_space(3))) void*)lds_dst,
        16, 0, 0);
}

__device__ __forceinline__ float dot4(const float4& a, const float4& b) {
    return a.x * b.x + a.y * b.y + a.z * b.z + a.w * b.w;
}

__global__ __launch_bounds__(NTHREADS, 2) void mmd_partial_kernel(
    const float* __restrict__ st, const float* __restrict__ sr,
    float* __restrict__ partial)
{
    __shared__ float4 buf[NBUF][8][TB];   // 64 KiB
    __shared__ float red[4][NPAIR];

    const int b    = blockIdx.x / BPG;
    const int blk  = blockIdx.x % BPG;
    const int c0   = blk * CHUNK4;
    const int tid  = threadIdx.x;
    const int wave = tid >> 6;
    const int lane = tid & 63;
    const int col  = tid & (TB - 1);   // column within tile (2 threads/col)
    const int set  = wave >> 1;        // 0: ss+cross(i=0,1)  1: rr+cross(i=2,3)

    const float4* stb = reinterpret_cast<const float4*>(st) + (size_t)b * MM * D4;
    const float4* srb = reinterpret_cast<const float4*>(sr) + (size_t)b * MM * D4;

    // This wave stages rows r0, r0+1 (rows 0-3 = st, 4-7 = sr).
    const int r0 = 2 * wave;
    const float4* g0 = (r0 < 4 ? stb + (size_t)r0 * D4
                                : srb + (size_t)(r0 - 4) * D4) + c0 + lane;
    const float4* g1 = (r0 + 1 < 4 ? stb + (size_t)(r0 + 1) * D4
                                    : srb + (size_t)(r0 - 3) * D4) + c0 + lane;

    // Stage s: this wave issues 4 x (64 lanes x 16B = 1KB). LDS dest is the
    // wave-uniform row base; HW adds lane*16. vmcnt is per-wave.
    auto stage = [&](int s) {
        const int m   = s % NBUF;
        const int off = s * TB;
        gl_lds16(g0 + off,      &buf[m][r0][0]);
        gl_lds16(g0 + off + 64, &buf[m][r0][64]);
        gl_lds16(g1 + off,      &buf[m][r0 + 1][0]);
        gl_lds16(g1 + off + 64, &buf[m][r0 + 1][64]);
    };

    float acc[NPAIR];
#pragma unroll
    for (int k = 0; k < NPAIR; ++k) acc[k] = 0.0f;

    stage(0);
    stage(1);
    stage(2);   // 3 stages (12 loads/wave, 12KB/wave) in flight

#pragma unroll
    for (int t = 0; t < NITER; ++t) {
        // My ds_reads of tile t-1 have sampled LDS -> safe for others to
        // overwrite buffer (t-1)%NBUF after the barrier.
        asm volatile("s_waitcnt lgkmcnt(0)" ::: "memory");
        // Wait for my stage-t loads only; stages t+1, t+2 stay in flight.
        if (t == NITER - 1)      asm volatile("s_waitcnt vmcnt(0)" ::: "memory");
        else if (t == NITER - 2) asm volatile("s_waitcnt vmcnt(4)" ::: "memory");
        else                     asm volatile("s_waitcnt vmcnt(8)" ::: "memory");
        // Raw barrier (no drain): all waves' stage-t rows are in LDS and all
        // waves are done reading tile t-1.
        __builtin_amdgcn_s_barrier();
        if (t + 3 < NITER) stage(t + 3);   // overwrite buffer of tile t-1

        const int m = t % NBUF;
        float4 x[8];
#pragma unroll
        for (int r = 0; r < 8; ++r) x[r] = buf[m][r][col];

        if (set == 0) {
            int a = 0;
#pragma unroll
            for (int i = 0; i < MM; ++i)
#pragma unroll
                for (int j = i; j < MM; ++j) { acc[a] += dot4(x[i], x[j]); ++a; }
#pragma unroll
            for (int i = 0; i < 2; ++i)
#pragma unroll
                for (int j = 0; j < MM; ++j) { acc[a] += dot4(x[i], x[4 + j]); ++a; }
        } else {
            int a = 0;
#pragma unroll
            for (int i = 0; i < MM; ++i)
#pragma unroll
                for (int j = i; j < MM; ++j) { acc[a] += dot4(x[4 + i], x[4 + j]); ++a; }
#pragma unroll
            for (int i = 2; i < 4; ++i)
#pragma unroll
                for (int j = 0; j < MM; ++j) { acc[a] += dot4(x[i], x[4 + j]); ++a; }
        }
    }

    // 64-lane butterfly reduce (sums the 64 columns this wave covered).
#pragma unroll
    for (int k = 0; k < NPAIR; ++k) {
        float v = acc[k];
        for (int off = 32; off > 0; off >>= 1) v += __shfl_down(v, off, 64);
        acc[k] = v;
    }
    if (lane == 0) {
#pragma unroll
        for (int k = 0; k < NPAIR; ++k) red[wave][k] = acc[k];
    }
    __syncthreads();

    // Global pair order: k=0..9 ss, 10..19 rr, 20..27 cross(i=0,1), 28..35 cross(i=2,3).
    // Transposed partial layout: partial[(k*NB + b)*BPG + blk].
    if (tid < NACC) {
        const int k = tid;
        float v;
        if (k < 10)       v = red[0][k]      + red[1][k];        // ss  (set A)
        else if (k < 20)  v = red[2][k - 10] + red[3][k - 10];   // rr  (set B)
        else if (k < 28)  v = red[0][10 + (k - 20)] + red[1][10 + (k - 20)]; // cross i=0,1
        else              v = red[2][10 + (k - 28)] + red[3][10 + (k - 28)]; // cross i=2,3
        partial[((size_t)k * NB + b) * BPG + blk] = v;
    }
}

__global__ __launch_bounds__(1024) void mmd_final_kernel(
    const float* __restrict__ partial, const float* __restrict__ wt,
    const float* __restrict__ wtout, float* __restrict__ out)
{
    __shared__ float acc_s[NACC][NB];   // [k][b]
    // Each (k,b) thread sums its 16 CONSECUTIVE partials (coalesced reads).
    for (int p = threadIdx.x; p < NB * NACC; p += 1024) {
        const int k = p >> 5;          // p / 32
        const int b = p & 31;          // p % 32
        const float* src = partial + ((size_t)k * NB + b) * BPG;
        float s = 0.0f;
#pragma unroll
        for (int q = 0; q < BPG; ++q) s += src[q];
        acc_s[k][b] = s;
    }
    __syncthreads();

    __shared__ float lds[NB];
    const int b = threadIdx.x;
    if (b < NB) {
        float a[NACC];
#pragma unroll
        for (int k = 0; k < NACC; ++k) a[k] = acc_s[k][b];   // lane b -> bank b

        float ss[MM][MM], rr[MM][MM], sg[MM][MM];
        {
            int k = 0;
            for (int i = 0; i < MM; ++i)
                for (int j = i; j < MM; ++j) { ss[i][j] = a[k]; ss[j][i] = a[k]; ++k; }
            for (int i = 0; i < MM; ++i)
                for (int j = i; j < MM; ++j) { rr[i][j] = a[k]; rr[j][i] = a[k]; ++k; }
            for (int i = 0; i < MM; ++i)
                for (int j = 0; j < MM; ++j) { sg[i][j] = a[k]; ++k; }
        }

        const float w    = wt[b];
        const float invD = 1.0f / (float)DD;  // sigma = 1
        auto kv = [&](float d2) -> float {
            d2 = fmaxf(d2, 1e-12f);
            float dist = sqrtf(d2) * invD;
            float e = -dist * w;
            e = fminf(fmaxf(e, -1e6f), 0.0f);
            return expf(e);
        };

        float mss = 0.0f, mrr = 0.0f, msr = 0.0f;
        for (int i = 0; i < MM; ++i) {
            for (int j = 0; j < MM; ++j) {
                mss += kv(ss[i][i] + ss[j][j] - 2.0f * ss[i][j]);
                mrr += kv(rr[i][i] + rr[j][j] - 2.0f * rr[i][j]);
                msr += kv(ss[i][i] + rr[j][j] - 2.0f * sg[i][j]);
            }
        }
        const float inv16 = 1.0f / 16.0f;
        float loss_raw = mss * inv16 + mrr * inv16 - 2.0f * (msr * inv16);
        lds[b] = wtout[b] * loss_raw;
    }
    __syncthreads();
    if (threadIdx.x == 0) {
        float s = 0.0f;
        for (int i = 0; i < NB; ++i) s += lds[i];
        out[0] = s / (float)NB;
    }
}

extern "C" void kernel_launch(void* const* d_in, const int* in_sizes, int n_in,
                              void* d_out, int out_size, void* d_ws, size_t ws_size,
                              hipStream_t stream) {
    const float* f_st  = (const float*)d_in[0];
    const float* f_sr  = (const float*)d_in[1];
    const float* wt    = (const float*)d_in[2];
    const float* wtout = (const float*)d_in[3];
    float* out     = (float*)d_out;
    float* partial = (float*)d_ws;   // NACC*NB*BPG floats = 73728 B

    mmd_partial_kernel<<<NBLOCKS, NTHREADS, 0, stream>>>(f_st, f_sr, partial);
    mmd_final_kernel<<<1, 1024, 0, stream>>>(partial, wt, wtout, out);
}